// Round 6
// baseline (1826.930 us; speedup 1.0000x reference)
//
#include <hip/hip_runtime.h>
#include <cstdint>
#include <cstddef>
#include <cmath>

// ---------------------------------------------------------------------------
// Round 6: R5 + (a) GEMM MFMA shape 16x16x32 -> 32x32x16 (ceiling 2075->2382
// TF, same LDS traffic per FLOP), (b) MP flattened to one thread per
// (node, fx4-chunk) for full thread utilization at all fd.
// Kept: XCD-ownership swizzle (R5: FETCH 704->158 MB), split-bf16 3-MFMA,
// 128x128x32 tiles, CSR message passing, segment pool.
// ---------------------------------------------------------------------------

#define EPS_BN 1e-5f

typedef unsigned short u16;
typedef short short8 __attribute__((ext_vector_type(8)));
typedef u16 u16x8 __attribute__((ext_vector_type(8)));
typedef u16 u16x4 __attribute__((ext_vector_type(4)));
typedef float fx4 __attribute__((ext_vector_type(4)));
typedef float fx16 __attribute__((ext_vector_type(16)));

__device__ __forceinline__ u16 bf16_rn(float f) {
  unsigned u = __float_as_uint(f);
  return (u16)((u + 0x7FFFu + ((u >> 16) & 1u)) >> 16);
}
__device__ __forceinline__ float bf16_f(u16 h) {
  return __uint_as_float(((unsigned)h) << 16);
}

// ---- XCD-ownership swizzle: bijection blockIdx -> (mt, nt) ----------------
// XCD x (presumed blockIdx%8) owns M-tiles {x, x+8, ...}; sweeps all N-tiles
// of one owned M-tile before advancing. Verified R5: A-slab fetched once.
__device__ __forceinline__ void map_tile(int b, int tm, int tn, int T,
                                         int& mt, int& nt) {
  const int x = b & 7;
  const int s = b >> 3;
  const int cap = ((tm - x + 7) >> 3) * tn;
  if (s < cap) {
    const int q = s / tn;
    mt = x + (q << 3);
    nt = s - q * tn;
    return;
  }
  int r = s - cap;
  for (int xp = 0; xp < x; ++xp) {
    const int nbp = (T - xp + 7) >> 3;
    const int capp = ((tm - xp + 7) >> 3) * tn;
    if (nbp > capp) r += nbp - capp;
  }
  for (int xq = 0; xq < 8; ++xq) {
    const int nbq = (T - xq + 7) >> 3;
    const int capq = ((tm - xq + 7) >> 3) * tn;
    const int def = capq - nbq;
    if (def > 0) {
      if (r < def) {
        const int sq = nbq + r;
        const int q = sq / tn;
        mt = xq + (q << 3);
        nt = sq - q * tn;
        return;
      }
      r -= def;
    }
  }
  mt = 0; nt = 0;  // unreachable
}

// ============================ MFMA GEMM ====================================
// C(MxN) = act(A @ B + bias). A: M x K (split bf16, or fp32 if SPLITA).
// B pre-transposed+split: Bhi/Blo are N x K bf16. OUTMODE 0: fp32 C.
// OUTMODE 1: bias+relu -> split bf16.
// Block 128x128, BK=32, 4 waves (2x2), wave tile 64x64 as 2x2 MFMA 32x32
// tiles x 2 k-chunks of 16; 3 MFMAs per tile pair (hihi, hilo, lohi).
// A/B frag: lane holds 8 contiguous k at row (lane&31), k-base (lane>>5)*8.
// C/D: col = lane&31, row = (reg&3) + 8*(reg>>2) + 4*(lane>>5)  [m74/m101].
template <int OUTMODE, bool SPLITA>
__global__ __launch_bounds__(256, 2) void gemm_mfma(
    const u16* __restrict__ Ahi, const u16* __restrict__ Alo,
    const float* __restrict__ Af,
    const u16* __restrict__ Bhi, const u16* __restrict__ Blo,
    const float* __restrict__ bias,
    float* __restrict__ Cf, u16* __restrict__ Chi, u16* __restrict__ Clo,
    int M, int N, int K, int tm, int tn) {
  constexpr int BM = 128, BN = 128, BK = 32, LDK = BK + 8;  // 40 u16 = 80 B row
  __shared__ __align__(16) u16 As[2][BM * LDK];
  __shared__ __align__(16) u16 Bs[2][BN * LDK];

  int bmt, bnt;
  map_tile(blockIdx.x, tm, tn, tm * tn, bmt, bnt);
  const int m0 = bmt * BM;
  const int n0 = bnt * BN;

  const int tid = threadIdx.x;
  const int lane = tid & 63;
  const int wid = tid >> 6;
  const int wm = (wid >> 1) * 64;
  const int wn = (wid & 1) * 64;
  const int l31 = lane & 31;
  const int kb = (lane >> 5) * 8;   // 0 or 8

  const int r1 = tid >> 2;        // rows 0..63
  const int r2 = r1 + 64;         // rows 64..127
  const int kc = (tid & 3) * 8;   // 0,8,16,24

  fx4 zf = {0.f, 0.f, 0.f, 0.f};
  fx16 acc[2][2];
#pragma unroll
  for (int a = 0; a < 2; ++a)
#pragma unroll
    for (int b = 0; b < 2; ++b)
#pragma unroll
      for (int r = 0; r < 16; ++r) acc[a][b][r] = 0.f;

  const u16x8 zz = {0, 0, 0, 0, 0, 0, 0, 0};

  for (int k0 = 0; k0 < K; k0 += BK) {
    const bool kok = (k0 + kc) < K;  // K%8==0 -> whole 8-chunk in/out
    u16x8 sa_h[2], sa_l[2], sb_h[2], sb_l[2];

#pragma unroll
    for (int it = 0; it < 2; ++it) {
      const int gm = m0 + (it ? r2 : r1);
      const bool ok = (gm < M) && kok;
      if (!SPLITA) {
        const size_t off = (size_t)gm * K + k0 + kc;
        sa_h[it] = ok ? *(const u16x8*)(Ahi + off) : zz;
        sa_l[it] = ok ? *(const u16x8*)(Alo + off) : zz;
      } else {
        fx4 f0 = zf, f1 = zf;
        if (ok) {
          const float* pp = Af + (size_t)gm * K + k0 + kc;
          f0 = *(const fx4*)pp;
          f1 = *(const fx4*)(pp + 4);
        }
        u16x8 h, l;
#pragma unroll
        for (int j = 0; j < 4; ++j) {
          u16 hb = bf16_rn(f0[j]);
          h[j] = hb;
          l[j] = bf16_rn(f0[j] - bf16_f(hb));
        }
#pragma unroll
        for (int j = 0; j < 4; ++j) {
          u16 hb = bf16_rn(f1[j]);
          h[4 + j] = hb;
          l[4 + j] = bf16_rn(f1[j] - bf16_f(hb));
        }
        sa_h[it] = h;
        sa_l[it] = l;
      }
    }
#pragma unroll
    for (int it = 0; it < 2; ++it) {
      const int gn = n0 + (it ? r2 : r1);
      const bool ok = (gn < N) && kok;
      const size_t off = (size_t)gn * K + k0 + kc;
      sb_h[it] = ok ? *(const u16x8*)(Bhi + off) : zz;
      sb_l[it] = ok ? *(const u16x8*)(Blo + off) : zz;
    }

    __syncthreads();
    {
      const int wo1 = r1 * LDK + kc;
      const int wo2 = r2 * LDK + kc;
      *(u16x8*)&As[0][wo1] = sa_h[0];
      *(u16x8*)&As[0][wo2] = sa_h[1];
      *(u16x8*)&As[1][wo1] = sa_l[0];
      *(u16x8*)&As[1][wo2] = sa_l[1];
      *(u16x8*)&Bs[0][wo1] = sb_h[0];
      *(u16x8*)&Bs[0][wo2] = sb_h[1];
      *(u16x8*)&Bs[1][wo1] = sb_l[0];
      *(u16x8*)&Bs[1][wo2] = sb_l[1];
    }
    __syncthreads();

    // frags: [m-tile or n-tile][k-chunk]
    short8 ah[2][2], al[2][2], bh[2][2], bl[2][2];
#pragma unroll
    for (int t = 0; t < 2; ++t)
#pragma unroll
      for (int c = 0; c < 2; ++c) {
        const int ra = (wm + t * 32 + l31) * LDK + c * 16 + kb;
        ah[t][c] = *(const short8*)&As[0][ra];
        al[t][c] = *(const short8*)&As[1][ra];
        const int rb = (wn + t * 32 + l31) * LDK + c * 16 + kb;
        bh[t][c] = *(const short8*)&Bs[0][rb];
        bl[t][c] = *(const short8*)&Bs[1][rb];
      }
#pragma unroll
    for (int c = 0; c < 2; ++c)
#pragma unroll
      for (int mt2 = 0; mt2 < 2; ++mt2)
#pragma unroll
        for (int nt2 = 0; nt2 < 2; ++nt2) {
          acc[mt2][nt2] = __builtin_amdgcn_mfma_f32_32x32x16_bf16(
              ah[mt2][c], bh[nt2][c], acc[mt2][nt2], 0, 0, 0);
          acc[mt2][nt2] = __builtin_amdgcn_mfma_f32_32x32x16_bf16(
              ah[mt2][c], bl[nt2][c], acc[mt2][nt2], 0, 0, 0);
          acc[mt2][nt2] = __builtin_amdgcn_mfma_f32_32x32x16_bf16(
              al[mt2][c], bh[nt2][c], acc[mt2][nt2], 0, 0, 0);
        }
  }

  // ---- epilogue: col = lane&31, row = (r&3) + 8*(r>>2) + 4*(lane>>5) ----
  const int rbase = 4 * (lane >> 5);
#pragma unroll
  for (int mt2 = 0; mt2 < 2; ++mt2)
#pragma unroll
    for (int nt2 = 0; nt2 < 2; ++nt2) {
      const int gn = n0 + wn + nt2 * 32 + l31;
      if (gn >= N) continue;
      const float bv = (OUTMODE == 1) ? bias[gn] : 0.f;
#pragma unroll
      for (int r = 0; r < 16; ++r) {
        const int gm = m0 + wm + mt2 * 32 + (r & 3) + 8 * (r >> 2) + rbase;
        if (gm < M) {
          float v = acc[mt2][nt2][r];
          if (OUTMODE == 1) {
            v = fmaxf(v + bv, 0.f);
            const u16 hb = bf16_rn(v);
            Chi[(size_t)gm * N + gn] = hb;
            Clo[(size_t)gm * N + gn] = bf16_rn(v - bf16_f(hb));
          } else {
            Cf[(size_t)gm * N + gn] = v;
          }
        }
      }
    }
}

// ================= weight prep: transpose + split (batched) ================
struct TSJob { const float* W; u16* Th; u16* Tl; int K; int N; int tiles_k; int base; };
struct TSJobs { TSJob j[12]; };

__global__ __launch_bounds__(256) void transpose_split_all(TSJobs jobs, int njobs) {
  const int b = blockIdx.x;
  int ji = 0;
  while (ji + 1 < njobs && jobs.j[ji + 1].base <= b) ++ji;
  const TSJob J = jobs.j[ji];
  const int t = b - J.base;
  const int k0 = (t % J.tiles_k) * 32;
  const int n0 = (t / J.tiles_k) * 32;
  __shared__ float tile[32][33];
  const int tx = threadIdx.x & 31, ty = threadIdx.x >> 5;
#pragma unroll
  for (int i = 0; i < 32; i += 8) {
    const int k = k0 + ty + i, n = n0 + tx;
    tile[ty + i][tx] = (k < J.K && n < J.N) ? J.W[(size_t)k * J.N + n] : 0.f;
  }
  __syncthreads();
#pragma unroll
  for (int i = 0; i < 32; i += 8) {
    const int n = n0 + ty + i, k = k0 + tx;
    if (n < J.N && k < J.K) {
      const float f = tile[tx][ty + i];
      const u16 hb = bf16_rn(f);
      J.Th[(size_t)n * J.K + k] = hb;
      J.Tl[(size_t)n * J.K + k] = bf16_rn(f - bf16_f(hb));
    }
  }
}

// ========================= Graph preprocessing =============================
__global__ void count_deg(const int* __restrict__ dst, int E, int* __restrict__ cnt) {
  int e = blockIdx.x * blockDim.x + threadIdx.x;
  if (e < E) atomicAdd(&cnt[dst[e]], 1);
}

__global__ void compute_dinv(const int* __restrict__ cnt, float* __restrict__ dinv, int N) {
  int i = blockIdx.x * blockDim.x + threadIdx.x;
  if (i < N) dinv[i] = rsqrtf((float)(cnt[i] + 1));  // +1 self-loop
}

__global__ void scan_block(const int* __restrict__ cnt, int* __restrict__ partial,
                           int* __restrict__ blocksum, int N) {
  __shared__ int s[256];
  const int t = threadIdx.x;
  const int i = blockIdx.x * 256 + t;
  int v = (i < N) ? cnt[i] : 0;
  s[t] = v;
  __syncthreads();
  for (int off = 1; off < 256; off <<= 1) {
    int u = (t >= off) ? s[t - off] : 0;
    __syncthreads();
    s[t] += u;
    __syncthreads();
  }
  if (i < N) partial[i] = s[t];
  if (t == 255) blocksum[blockIdx.x] = s[255];
}

__global__ void scan_sums(int* __restrict__ blocksum, int NB) {
  __shared__ int s[256];
  const int t = threadIdx.x;
  int v = (t < NB) ? blocksum[t] : 0;
  s[t] = v;
  __syncthreads();
  for (int off = 1; off < 256; off <<= 1) {
    int u = (t >= off) ? s[t - off] : 0;
    __syncthreads();
    s[t] += u;
    __syncthreads();
  }
  if (t < NB) blocksum[t] = s[t] - v;  // exclusive
}

__global__ void finalize_rowptr(const int* __restrict__ partial, const int* __restrict__ blockoff,
                                int* __restrict__ rowptr, int N) {
  int i = blockIdx.x * 256 + threadIdx.x;
  if (i < N) rowptr[i + 1] = partial[i] + blockoff[blockIdx.x];
  if (i == 0) rowptr[0] = 0;
}

__global__ void fill_csr(const int* __restrict__ src, const int* __restrict__ dst, int E,
                         const int* __restrict__ rowptr, int* __restrict__ cursor,
                         int* __restrict__ colidx) {
  int e = blockIdx.x * blockDim.x + threadIdx.x;
  if (e < E) {
    int d = dst[e];
    int p = atomicAdd(&cursor[d], 1);
    colidx[rowptr[d] + p] = src[e];
  }
}

// ================= Message passing + bias + BN + ReLU ======================
// flat: one thread per (dst node, fx4 chunk); 4-wide edge unroll.
__global__ void mp_bn_relu(
    const float* __restrict__ H, const int* __restrict__ rowptr,
    const int* __restrict__ colidx, const float* __restrict__ dinv,
    const float* __restrict__ gb, const float* __restrict__ gamma,
    const float* __restrict__ beta, const float* __restrict__ mean,
    const float* __restrict__ var,
    u16* __restrict__ Xh, u16* __restrict__ Xl, int N, int F, int chunks) {
  const int gid = blockIdx.x * blockDim.x + threadIdx.x;
  if (gid >= N * chunks) return;
  const int i = gid / chunks;
  const int c = gid - i * chunks;
  const float di = dinv[i];
  const size_t rowi = (size_t)i * F + c * 4;
  fx4 acc = (di * di) * *(const fx4*)(H + rowi);
  const int e0 = rowptr[i], e1 = rowptr[i + 1];
  int e = e0;
  for (; e + 4 <= e1; e += 4) {
    const int s0 = colidx[e + 0], s1 = colidx[e + 1];
    const int s2 = colidx[e + 2], s3 = colidx[e + 3];
    const float w0 = di * dinv[s0], w1 = di * dinv[s1];
    const float w2 = di * dinv[s2], w3 = di * dinv[s3];
    const fx4 v0 = *(const fx4*)(H + (size_t)s0 * F + c * 4);
    const fx4 v1 = *(const fx4*)(H + (size_t)s1 * F + c * 4);
    const fx4 v2 = *(const fx4*)(H + (size_t)s2 * F + c * 4);
    const fx4 v3 = *(const fx4*)(H + (size_t)s3 * F + c * 4);
    acc += w0 * v0;
    acc += w1 * v1;
    acc += w2 * v2;
    acc += w3 * v3;
  }
  for (; e < e1; ++e) {
    const int s = colidx[e];
    acc += (di * dinv[s]) * *(const fx4*)(H + (size_t)s * F + c * 4);
  }
  u16x4 oh, ol;
#pragma unroll
  for (int j = 0; j < 4; ++j) {
    const int col = c * 4 + j;
    float v = (acc[j] + gb[col] - mean[col]) * rsqrtf(var[col] + EPS_BN) * gamma[col] + beta[col];
    v = fmaxf(v, 0.f);
    const u16 hb = bf16_rn(v);
    oh[j] = hb;
    ol[j] = bf16_rn(v - bf16_f(hb));
  }
  *(u16x4*)(Xh + rowi) = oh;
  *(u16x4*)(Xl + rowi) = ol;
}

// ========================= global max pool (segments) ======================
// batch is sorted -> each group is a contiguous node range (binary search).
__global__ void pool_seg(const u16* __restrict__ Xh, const u16* __restrict__ Xl,
                         const int* __restrict__ batch, float* __restrict__ out,
                         int N, int F) {
  const int g = blockIdx.x;
  int lo = 0, hi = N;
  while (lo < hi) { int m = (lo + hi) >> 1; if (batch[m] < g) lo = m + 1; else hi = m; }
  const int s0 = lo;
  hi = N;
  while (lo < hi) { int m = (lo + hi) >> 1; if (batch[m] <= g) lo = m + 1; else hi = m; }
  const int s1 = lo;
  const int c = threadIdx.x;
  if (c * 4 >= F) return;
  fx4 mx = {-INFINITY, -INFINITY, -INFINITY, -INFINITY};
  for (int i = s0; i < s1; ++i) {
    const size_t off = (size_t)i * F + c * 4;
    const u16x4 h = *(const u16x4*)(Xh + off);
    const u16x4 l = *(const u16x4*)(Xl + off);
#pragma unroll
    for (int j = 0; j < 4; ++j) mx[j] = fmaxf(mx[j], bf16_f(h[j]) + bf16_f(l[j]));
  }
  *(fx4*)(out + (size_t)g * F + c * 4) = mx;
}

// =========================== launch ========================================
extern "C" void kernel_launch(void* const* d_in, const int* in_sizes, int n_in,
                              void* d_out, int out_size, void* d_ws, size_t ws_size,
                              hipStream_t stream) {
  const float* x = (const float*)d_in[0];
  const int* edges = (const int*)d_in[1];
  const int* batch = (const int*)d_in[2];
  const int E = in_sizes[1] / 2;
  const int Nn = in_sizes[2];

  static const int FDS[4] = {80, 160, 400, 600};
  static const int DINS[4] = {3072, 80, 160, 400};
  const float *wa[4], *ba[4], *wb[4], *bb[4], *gw[4], *gb[4], *gamma[4], *beta[4], *mean[4], *var[4];
  for (int i = 0; i < 4; ++i) {
    const int b = 3 + 10 * i;
    wa[i] = (const float*)d_in[b + 0];
    ba[i] = (const float*)d_in[b + 1];
    wb[i] = (const float*)d_in[b + 2];
    bb[i] = (const float*)d_in[b + 3];
    gw[i] = (const float*)d_in[b + 4];
    gb[i] = (const float*)d_in[b + 5];
    gamma[i] = (const float*)d_in[b + 6];
    beta[i] = (const float*)d_in[b + 7];
    mean[i] = (const float*)d_in[b + 8];
    var[i] = (const float*)d_in[b + 9];
  }

  // ---- workspace carve ----
  char* p = (char*)d_ws;
  auto alloc = [&](size_t bytes) {
    char* r = p;
    p += (bytes + 255) & ~(size_t)255;
    return r;
  };
  u16* actA_h = (u16*)alloc((size_t)Nn * 2400 * 2);  // H1 hi; H3(fp32) aliases head
  u16* actA_l = (u16*)alloc((size_t)Nn * 2400 * 2);  // H1 lo
  u16* actB_h = (u16*)alloc((size_t)Nn * 600 * 2);   // X / H2 hi
  u16* actB_l = (u16*)alloc((size_t)Nn * 600 * 2);   // X / H2 lo
  float* H3 = (float*)actA_h;  // H1 dead when G3 writes H3; MP consumes before next G1

  u16 *waT_h[4], *waT_l[4], *wbT_h[4], *wbT_l[4], *gwT_h[4], *gwT_l[4];
  for (int i = 0; i < 4; ++i) {
    const size_t s1 = (size_t)DINS[i] * 4 * FDS[i];
    const size_t s2 = (size_t)4 * FDS[i] * FDS[i];
    const size_t s3 = (size_t)FDS[i] * FDS[i];
    waT_h[i] = (u16*)alloc(s1 * 2);
    waT_l[i] = (u16*)alloc(s1 * 2);
    wbT_h[i] = (u16*)alloc(s2 * 2);
    wbT_l[i] = (u16*)alloc(s2 * 2);
    gwT_h[i] = (u16*)alloc(s3 * 2);
    gwT_l[i] = (u16*)alloc(s3 * 2);
  }

  int* cnt = (int*)alloc((size_t)Nn * sizeof(int));
  int* cursor = (int*)alloc((size_t)Nn * sizeof(int));
  int* partial = (int*)alloc((size_t)Nn * sizeof(int));
  int* blocksum = (int*)alloc(256 * sizeof(int));
  int* rowptr = (int*)alloc((size_t)(Nn + 1) * sizeof(int));
  int* colidx = (int*)alloc((size_t)E * sizeof(int));
  float* dinv = (float*)alloc((size_t)Nn * sizeof(float));

  const int* srcIdx = edges;
  const int* dstIdx = edges + E;

  // ---- weight prep: one batched launch for all 12 transpose+splits ----
  {
    TSJobs jobs;
    int base = 0, ji = 0;
    auto addjob = [&](const float* W, int K, int Ncols, u16* Th, u16* Tl) {
      const int tk = (K + 31) / 32, tn = (Ncols + 31) / 32;
      jobs.j[ji++] = TSJob{W, Th, Tl, K, Ncols, tk, base};
      base += tk * tn;
    };
    for (int i = 0; i < 4; ++i) {
      addjob(wa[i], DINS[i], 4 * FDS[i], waT_h[i], waT_l[i]);
      addjob(wb[i], 4 * FDS[i], FDS[i], wbT_h[i], wbT_l[i]);
      addjob(gw[i], FDS[i], FDS[i], gwT_h[i], gwT_l[i]);
    }
    transpose_split_all<<<base, 256, 0, stream>>>(jobs, 12);
  }

  // ---- CSR build ----
  hipMemsetAsync(cnt, 0, (size_t)Nn * sizeof(int), stream);
  hipMemsetAsync(cursor, 0, (size_t)Nn * sizeof(int), stream);

  const int EB = (E + 255) / 256;
  const int NB = (Nn + 255) / 256;
  count_deg<<<EB, 256, 0, stream>>>(dstIdx, E, cnt);
  compute_dinv<<<NB, 256, 0, stream>>>(cnt, dinv, Nn);
  scan_block<<<NB, 256, 0, stream>>>(cnt, partial, blocksum, Nn);
  scan_sums<<<1, 256, 0, stream>>>(blocksum, NB);
  finalize_rowptr<<<NB, 256, 0, stream>>>(partial, blocksum, rowptr, Nn);
  fill_csr<<<EB, 256, 0, stream>>>(srcIdx, dstIdx, E, rowptr, cursor, colidx);

  // ---- layers ----
  for (int i = 0; i < 4; ++i) {
    const int fd = FDS[i];
    const int hid = 4 * fd;
    const int din = DINS[i];
    const int tm = (Nn + 127) / 128;

    // G1: X @ wa + ba, relu -> H1 (split)
    {
      const int tn = (hid + 127) / 128;
      if (i == 0) {
        gemm_mfma<1, true><<<tm * tn, 256, 0, stream>>>(
            nullptr, nullptr, x, waT_h[0], waT_l[0], ba[0],
            nullptr, actA_h, actA_l, Nn, hid, din, tm, tn);
      } else {
        gemm_mfma<1, false><<<tm * tn, 256, 0, stream>>>(
            actB_h, actB_l, nullptr, waT_h[i], waT_l[i], ba[i],
            nullptr, actA_h, actA_l, Nn, hid, din, tm, tn);
      }
    }
    // G2: H1 @ wb + bb, relu -> H2 (split)
    {
      const int tn = (fd + 127) / 128;
      gemm_mfma<1, false><<<tm * tn, 256, 0, stream>>>(
          actA_h, actA_l, nullptr, wbT_h[i], wbT_l[i], bb[i],
          nullptr, actB_h, actB_l, Nn, fd, hid, tm, tn);
    }
    // G3: H2 @ gw -> H3 (fp32, aliases H1 region)
    {
      const int tn = (fd + 127) / 128;
      gemm_mfma<0, false><<<tm * tn, 256, 0, stream>>>(
          actB_h, actB_l, nullptr, gwT_h[i], gwT_l[i], nullptr,
          H3, nullptr, nullptr, Nn, fd, fd, tm, tn);
    }
    // MP + bias + BN + ReLU -> X_next (split); one thread per (node, chunk)
    const int chunks = fd / 4;
    const int total = Nn * chunks;
    mp_bn_relu<<<(total + 255) / 256, 256, 0, stream>>>(
        H3, rowptr, colidx, dinv, gb[i], gamma[i],
        beta[i], mean[i], var[i], actB_h, actB_l, Nn, fd, chunks);
  }

  pool_seg<<<out_size / 600, 192, 0, stream>>>(actB_h, actB_l, batch, (float*)d_out, Nn, 600);
}